// Round 3
// baseline (299.830 us; speedup 1.0000x reference)
//
#include <hip/hip_runtime.h>
#include <math.h>

#define BB 16
#define HH 512
#define WW 512
#define CC 4

#define SEGS 32
#define RPT  (HH / SEGS)      // 16 rows per thread in the column scan

// ---------------------------------------------------------------------------
// K1a: one block per image row. Read defgrad float2 once, compute logistic of
// both channels; inclusive row-scan of gx -> xs plane; write gy plane.
// grid: BB*HH = 8192 blocks x 512 threads.
// ---------------------------------------------------------------------------
__global__ __launch_bounds__(512)
void rowprep_kernel(const float2* __restrict__ defgrad,
                    float* __restrict__ xs, int xss,
                    float* __restrict__ gy, int gys) {
    const int row = blockIdx.x;            // b*HH + h
    const int w   = threadIdx.x;
    const size_t pix = (size_t)row * WW + w;

    const float2 v = defgrad[pix];
    const float gxv = 2.0f / (1.0f + expf(-v.x));
    const float gyv = 2.0f / (1.0f + expf(-v.y));

    // inclusive scan of gxv across 512 threads
    const int lane = w & 63;
    const int wv   = w >> 6;
    float x = gxv;
#pragma unroll
    for (int off = 1; off < 64; off <<= 1) {
        float n = __shfl_up(x, off, 64);
        if (lane >= off) x += n;
    }
    __shared__ float wsum[8];
    if (lane == 63) wsum[wv] = x;
    __syncthreads();
    float pref = 0.f;
    for (int j = 0; j < wv; ++j) pref += wsum[j];

    xs[pix * (size_t)xss] = x + pref;
    gy[pix * (size_t)gys] = gyv;
}

// ---------------------------------------------------------------------------
// K1b: column-inclusive scan of the (already-logistic) gy plane -> ys plane.
// grid: BB*(WW/32) = 256 blocks x 1024 threads (32 cols x 32 h-segments).
// All 16 loads are prefetched in a dedicated loop (max MLP) before any math.
// ---------------------------------------------------------------------------
__global__ __launch_bounds__(1024)
void colscan_kernel(const float* __restrict__ gy, int gys,
                    float* __restrict__ ys, int yss) {
    const int wt  = blockIdx.x % (WW / 32);
    const int b   = blockIdx.x / (WW / 32);
    const int col = threadIdx.x & 31;
    const int seg = threadIdx.x >> 5;          // 0..31
    const int w   = wt * 32 + col;
    const int h0  = seg * RPT;
    const size_t rowbase = ((size_t)b * HH + h0) * WW + w;

    float vals[RPT];
#pragma unroll
    for (int i = 0; i < RPT; ++i)              // pure load loop -> 16 in flight
        vals[i] = gy[(rowbase + (size_t)i * WW) * (size_t)gys];

    float s = 0.f;
#pragma unroll
    for (int i = 0; i < RPT; ++i) s += vals[i];

    __shared__ float part[SEGS][32];
    part[seg][col] = s;
    __syncthreads();

    float run = 0.f;
    for (int j = 0; j < seg; ++j) run += part[j][col];   // exclusive seg prefix

#pragma unroll
    for (int i = 0; i < RPT; ++i) {
        run += vals[i];
        ys[(rowbase + (size_t)i * WW) * (size_t)yss] = run;
    }
}

// ---------------------------------------------------------------------------
// K2: pure sampler — no LDS, no syncs. Each thread handles 4 consecutive
// pixels (float4 loads of xs/ys when planar), issuing 16 independent bilinear
// gathers. XCD-contiguous swizzle: each XCD sweeps 2 images in row order.
// grid: 1024 blocks x 1024 threads.
// ---------------------------------------------------------------------------
__global__ __launch_bounds__(1024)
void sample_kernel(const float4* __restrict__ im4,
                   const float*  __restrict__ xs, int xss,
                   const float*  __restrict__ ys, int yss,
                   const float*  __restrict__ affine,
                   float4* __restrict__ out4,
                   float*  __restrict__ grid3) {
    const int blk = blockIdx.x;                          // 0..1023
    const int gt  = (blk & 7) * 128 + (blk >> 3);        // XCD-contiguous
    const int q   = gt * 1024 + threadIdx.x;             // quad index
    const size_t p0 = (size_t)q * 4;                     // first pixel
    const int b = (int)(p0 >> 18);                       // /(HH*WW)

    const float* Ab = affine + b * 9;
    const float a00 = Ab[0] + 1.f, a01 = Ab[1], a02 = Ab[2];
    const float a10 = Ab[3], a11 = Ab[4] + 1.f, a12 = Ab[5];
    const float a20 = Ab[6], a21 = Ab[7], a22 = Ab[8] + 1.f;

    float xsv[4], ysv[4];
    if (xss == 1 && yss == 1) {
        const float4 tx = ((const float4*)xs)[q];
        const float4 ty = ((const float4*)ys)[q];
        xsv[0] = tx.x; xsv[1] = tx.y; xsv[2] = tx.z; xsv[3] = tx.w;
        ysv[0] = ty.x; ysv[1] = ty.y; ysv[2] = ty.z; ysv[3] = ty.w;
    } else {
#pragma unroll
        for (int i = 0; i < 4; ++i) {
            xsv[i] = xs[(p0 + i) * (size_t)xss];
            ysv[i] = ys[(p0 + i) * (size_t)yss];
        }
    }

    const size_t ibase = (size_t)b * HH * WW;
    float xg[4], yg[4], wgv[4], wa[4], wb[4], wc[4], wd[4];
    size_t ia[4], ib_[4], ic[4], id[4];
#pragma unroll
    for (int i = 0; i < 4; ++i) {
        xg[i]  = a00 * xsv[i] + a01 * ysv[i] + a02;
        yg[i]  = a10 * xsv[i] + a11 * ysv[i] + a12;
        wgv[i] = a20 * xsv[i] + a21 * ysv[i] + a22;
        const int ix = (int)floorf(xg[i]);
        const int iy = (int)floorf(yg[i]);
        const int x0 = min(max(ix,     0), WW - 1);
        const int x1 = min(max(ix + 1, 0), WW - 1);
        const int y0 = min(max(iy,     0), HH - 1);
        const int y1 = min(max(iy + 1, 0), HH - 1);
        const float x0f = (float)x0, x1f = (float)x1;
        const float y0f = (float)y0, y1f = (float)y1;
        wa[i] = (x1f - xg[i]) * (y1f - yg[i]);
        wb[i] = (x1f - xg[i]) * (yg[i] - y0f);
        wc[i] = (xg[i] - x0f) * (y1f - yg[i]);
        wd[i] = (xg[i] - x0f) * (yg[i] - y0f);
        ia[i]  = ibase + (size_t)y0 * WW + x0;
        ib_[i] = ibase + (size_t)y1 * WW + x0;
        ic[i]  = ibase + (size_t)y0 * WW + x1;
        id[i]  = ibase + (size_t)y1 * WW + x1;
    }

    float4 o[4];
#pragma unroll
    for (int i = 0; i < 4; ++i) {
        const float4 Ia = im4[ia[i]];
        const float4 Ib = im4[ib_[i]];
        const float4 Ic = im4[ic[i]];
        const float4 Id = im4[id[i]];
        o[i].x = wa[i] * Ia.x + wb[i] * Ib.x + wc[i] * Ic.x + wd[i] * Id.x;
        o[i].y = wa[i] * Ia.y + wb[i] * Ib.y + wc[i] * Ic.y + wd[i] * Id.y;
        o[i].z = wa[i] * Ia.z + wb[i] * Ib.z + wc[i] * Ic.z + wd[i] * Id.z;
        o[i].w = wa[i] * Ia.w + wb[i] * Ib.w + wc[i] * Ic.w + wd[i] * Id.w;
    }

#pragma unroll
    for (int i = 0; i < 4; ++i) out4[p0 + i] = o[i];

    if (xss == 1 && yss == 1) {
        float4* g4 = (float4*)grid3;
        float4 g0, g1, g2;
        g0.x = xg[0];  g0.y = yg[0];  g0.z = wgv[0]; g0.w = xg[1];
        g1.x = yg[1];  g1.y = wgv[1]; g1.z = xg[2];  g1.w = yg[2];
        g2.x = wgv[2]; g2.y = xg[3];  g2.z = yg[3];  g2.w = wgv[3];
        g4[(size_t)q * 3 + 0] = g0;
        g4[(size_t)q * 3 + 1] = g1;
        g4[(size_t)q * 3 + 2] = g2;
    } else {
#pragma unroll
        for (int i = 0; i < 4; ++i) {
            grid3[(p0 + i) * 3 + 0] = xg[i];
            grid3[(p0 + i) * 3 + 1] = yg[i];
            grid3[(p0 + i) * 3 + 2] = wgv[i];
        }
    }
}

extern "C" void kernel_launch(void* const* d_in, const int* in_sizes, int n_in,
                              void* d_out, int out_size, void* d_ws, size_t ws_size,
                              hipStream_t stream) {
    const float* im      = (const float*)d_in[0];
    const float* defgrad = (const float*)d_in[1];
    const float* affine  = (const float*)d_in[2];

    float* out   = (float*)d_out;
    float* grid3 = out + (size_t)BB * HH * WW * CC;

    const size_t plane = (size_t)BB * HH * WW;
    const size_t plane_bytes = plane * sizeof(float);

    // scratch planes: xs, ys, gy. Prefer planar workspace; fall back to
    // stashing inside grid3 slots (each K2 thread reads only its own stash
    // before overwriting -> race-free).
    float *xsp, *ysp, *gyp;
    int xss, yss, gys;
    if (ws_size >= 3 * plane_bytes) {
        xsp = (float*)d_ws;             xss = 1;
        ysp = (float*)d_ws + plane;     yss = 1;
        gyp = (float*)d_ws + 2 * plane; gys = 1;
    } else if (ws_size >= 2 * plane_bytes) {
        xsp = (float*)d_ws;             xss = 1;
        ysp = (float*)d_ws + plane;     yss = 1;
        gyp = grid3 + 2;                gys = 3;
    } else if (ws_size >= plane_bytes) {
        xsp = grid3 + 0;                xss = 3;
        ysp = (float*)d_ws;             yss = 1;
        gyp = grid3 + 2;                gys = 3;
    } else {
        xsp = grid3 + 0;                xss = 3;
        ysp = grid3 + 1;                yss = 3;
        gyp = grid3 + 2;                gys = 3;
    }

    rowprep_kernel<<<BB * HH, 512, 0, stream>>>(
        (const float2*)defgrad, xsp, xss, gyp, gys);

    colscan_kernel<<<BB * (WW / 32), 1024, 0, stream>>>(
        gyp, gys, ysp, yss);

    sample_kernel<<<1024, 1024, 0, stream>>>(
        (const float4*)im, xsp, xss, ysp, yss, affine,
        (float4*)out, grid3);
}